// Round 1
// baseline (4245.980 us; speedup 1.0000x reference)
//
#include <hip/hip_runtime.h>

#define N_NODES 100000
#define N_EDGES 6400000
#define D 12

// Scatter phase: one thread per edge.
// agg[dst] += x[src]; cnt[dst] += 1
__global__ __launch_bounds__(256) void scatter_kernel(
    const int* __restrict__ ei,     // [2, E]: src row then dst row
    const float* __restrict__ x,    // [N, D]
    float* __restrict__ agg,        // [N, D]
    float* __restrict__ cnt)        // [N]
{
    int e = blockIdx.x * blockDim.x + threadIdx.x;
    if (e >= N_EDGES) return;
    int src = ei[e];
    int dst = ei[N_EDGES + e];

    // x rows are 48 B (12 floats) -> three float4 loads, 16B-aligned.
    const float4* xr = (const float4*)(x + (size_t)src * D);
    float4 a = xr[0];
    float4 b4 = xr[1];
    float4 c = xr[2];

    float* dr = agg + (size_t)dst * D;
    atomicAdd(dr + 0,  a.x);
    atomicAdd(dr + 1,  a.y);
    atomicAdd(dr + 2,  a.z);
    atomicAdd(dr + 3,  a.w);
    atomicAdd(dr + 4,  b4.x);
    atomicAdd(dr + 5,  b4.y);
    atomicAdd(dr + 6,  b4.z);
    atomicAdd(dr + 7,  b4.w);
    atomicAdd(dr + 8,  c.x);
    atomicAdd(dr + 9,  c.y);
    atomicAdd(dr + 10, c.z);
    atomicAdd(dr + 11, c.w);
    atomicAdd(cnt + dst, 1.0f);
}

// Finalize: one thread per node.
// out[i] = (agg[i]/max(cnt[i],1)) @ W_l^T + x[i] @ W_r^T + b
__global__ __launch_bounds__(256) void finalize_kernel(
    const float* __restrict__ x,
    const float* __restrict__ Wl,   // [D, D] row-major
    const float* __restrict__ Wr,   // [D, D] row-major
    const float* __restrict__ bias, // [D]
    const float* __restrict__ agg,
    const float* __restrict__ cnt,
    float* __restrict__ out)
{
    __shared__ float sWl[D * D];
    __shared__ float sWr[D * D];
    __shared__ float sb[D];
    int t = threadIdx.x;
    if (t < D * D) {
        sWl[t] = Wl[t];
        sWr[t] = Wr[t];
    }
    if (t < D) sb[t] = bias[t];
    __syncthreads();

    int i = blockIdx.x * blockDim.x + t;
    if (i >= N_NODES) return;

    float inv = 1.0f / fmaxf(cnt[i], 1.0f);

    float m[D], xi[D];
    const float4* ar = (const float4*)(agg + (size_t)i * D);
    const float4* xr = (const float4*)(x + (size_t)i * D);
    float4 a0 = ar[0], a1 = ar[1], a2 = ar[2];
    float4 x0 = xr[0], x1 = xr[1], x2 = xr[2];
    m[0] = a0.x * inv; m[1] = a0.y * inv; m[2]  = a0.z * inv; m[3]  = a0.w * inv;
    m[4] = a1.x * inv; m[5] = a1.y * inv; m[6]  = a1.z * inv; m[7]  = a1.w * inv;
    m[8] = a2.x * inv; m[9] = a2.y * inv; m[10] = a2.z * inv; m[11] = a2.w * inv;
    xi[0] = x0.x; xi[1] = x0.y; xi[2]  = x0.z; xi[3]  = x0.w;
    xi[4] = x1.x; xi[5] = x1.y; xi[6]  = x1.z; xi[7]  = x1.w;
    xi[8] = x2.x; xi[9] = x2.y; xi[10] = x2.z; xi[11] = x2.w;

    float o[D];
#pragma unroll
    for (int oo = 0; oo < D; ++oo) {
        float acc = sb[oo];
#pragma unroll
        for (int d = 0; d < D; ++d) {
            acc += m[d] * sWl[oo * D + d];
            acc += xi[d] * sWr[oo * D + d];
        }
        o[oo] = acc;
    }

    float4* orow = (float4*)(out + (size_t)i * D);
    orow[0] = make_float4(o[0], o[1], o[2], o[3]);
    orow[1] = make_float4(o[4], o[5], o[6], o[7]);
    orow[2] = make_float4(o[8], o[9], o[10], o[11]);
}

extern "C" void kernel_launch(void* const* d_in, const int* in_sizes, int n_in,
                              void* d_out, int out_size, void* d_ws, size_t ws_size,
                              hipStream_t stream) {
    const float* x    = (const float*)d_in[0];
    const float* Wl   = (const float*)d_in[1];
    const float* Wr   = (const float*)d_in[2];
    const float* bias = (const float*)d_in[3];
    const int*   ei   = (const int*)d_in[4];
    float* out = (float*)d_out;

    float* agg = (float*)d_ws;
    float* cnt = agg + (size_t)N_NODES * D;

    // Workspace is poisoned 0xAA before every call — zero agg + cnt.
    hipMemsetAsync(d_ws, 0, ((size_t)N_NODES * D + N_NODES) * sizeof(float), stream);

    dim3 blk(256);
    dim3 grid_e((N_EDGES + 255) / 256);
    scatter_kernel<<<grid_e, blk, 0, stream>>>(ei, x, agg, cnt);

    dim3 grid_n((N_NODES + 255) / 256);
    finalize_kernel<<<grid_n, blk, 0, stream>>>(x, Wl, Wr, bias, agg, cnt, out);
}

// Round 2
// 838.286 us; speedup vs baseline: 5.0651x; 5.0651x over previous
//
#include <hip/hip_runtime.h>

#define N_NODES 100000
#define N_EDGES 6400000
#define D 12

#define SLOG 7
#define SSZ  128                       // nodes per bucket
#define NB   ((N_NODES + SSZ - 1) / SSZ)   // 782 buckets
#define NBLK 128                       // hist/scatter blocks
#define EPB  ((N_EDGES + NBLK - 1) / NBLK) // 50000 edges per block

// ---------------- Fast path: counting-sort by dst bucket, LDS aggregation ---

// Pass 1: per-block histogram of dst buckets.
__global__ __launch_bounds__(256) void hist_kernel(
    const int* __restrict__ ei, int* __restrict__ hist)
{
    __shared__ int h[NB];
    for (int i = threadIdx.x; i < NB; i += 256) h[i] = 0;
    __syncthreads();
    int blk = blockIdx.x;
    int start = blk * EPB;
    int end = min(start + EPB, N_EDGES);
    for (int e = start + (int)threadIdx.x; e < end; e += 256) {
        int dst = ei[N_EDGES + e];
        atomicAdd(&h[dst >> SLOG], 1);
    }
    __syncthreads();
    for (int i = threadIdx.x; i < NB; i += 256) hist[blk * NB + i] = h[i];
}

// Pass 2: single block. Column sums -> exclusive scan over bins ->
// expand per-(block,bin) starting offsets.
__global__ __launch_bounds__(1024) void scan_kernel(
    const int* __restrict__ hist, int* __restrict__ off)
{
    __shared__ int totals[NB];
    __shared__ int scanbuf[1024];
    int tid = threadIdx.x;

    for (int bin = tid; bin < NB; bin += 1024) {
        int s = 0;
        for (int blk = 0; blk < NBLK; ++blk) s += hist[blk * NB + bin];
        totals[bin] = s;
    }
    __syncthreads();

    // Hillis-Steele inclusive scan over 1024 (padded), then convert to exclusive.
    int v = (tid < NB) ? totals[tid] : 0;
    scanbuf[tid] = v;
    __syncthreads();
    for (int o = 1; o < 1024; o <<= 1) {
        int t = (tid >= o) ? scanbuf[tid - o] : 0;
        __syncthreads();
        scanbuf[tid] += t;
        __syncthreads();
    }
    if (tid < NB) totals[tid] = scanbuf[tid] - v;   // exclusive base per bin
    __syncthreads();

    for (int bin = tid; bin < NB; bin += 1024) {
        int run = totals[bin];
        for (int blk = 0; blk < NBLK; ++blk) {
            int c = hist[blk * NB + bin];
            off[blk * NB + bin] = run;
            run += c;
        }
    }
}

// Pass 3: scatter edges into bucket-sorted order, packed 4B per edge.
__global__ __launch_bounds__(256) void scatter_sort_kernel(
    const int* __restrict__ ei, const int* __restrict__ off,
    unsigned int* __restrict__ sorted)
{
    __shared__ int cur[NB];
    int blk = blockIdx.x;
    for (int i = threadIdx.x; i < NB; i += 256) cur[i] = off[blk * NB + i];
    __syncthreads();
    int start = blk * EPB;
    int end = min(start + EPB, N_EDGES);
    for (int e = start + (int)threadIdx.x; e < end; e += 256) {
        int src = ei[e];
        int dst = ei[N_EDGES + e];
        int bin = dst >> SLOG;
        int pos = atomicAdd(&cur[bin], 1);
        sorted[pos] = ((unsigned)src << SLOG) | (unsigned)(dst & (SSZ - 1));
    }
}

// Pass 4: one block per bucket. LDS-aggregate the bucket's edges, then
// fused finalize: out = (agg/max(cnt,1)) @ Wl^T + x @ Wr^T + b.
__global__ __launch_bounds__(256) void agg_finalize_kernel(
    const unsigned int* __restrict__ sorted, const int* __restrict__ off,
    const float* __restrict__ x, const float* __restrict__ Wl,
    const float* __restrict__ Wr, const float* __restrict__ bias,
    float* __restrict__ out)
{
    __shared__ float agg[SSZ * D];
    __shared__ float cnt[SSZ];
    __shared__ float sWl[D * D], sWr[D * D], sb[D];
    int t = threadIdx.x;
    int b = blockIdx.x;

    for (int i = t; i < SSZ * D; i += 256) agg[i] = 0.f;
    if (t < SSZ) cnt[t] = 0.f;
    if (t < D * D) { sWl[t] = Wl[t]; sWr[t] = Wr[t]; }
    if (t < D) sb[t] = bias[t];
    __syncthreads();

    int start = off[b];                                // off row 0 = bin bases
    int end = (b + 1 < NB) ? off[b + 1] : N_EDGES;
    for (int e = start + t; e < end; e += 256) {
        unsigned p = sorted[e];
        int src = (int)(p >> SLOG);
        int loc = (int)(p & (SSZ - 1));
        const float4* xr = (const float4*)(x + (size_t)src * D);
        float4 a = xr[0], b4 = xr[1], c = xr[2];
        float* ar = &agg[loc * D];
        atomicAdd(ar + 0,  a.x);
        atomicAdd(ar + 1,  a.y);
        atomicAdd(ar + 2,  a.z);
        atomicAdd(ar + 3,  a.w);
        atomicAdd(ar + 4,  b4.x);
        atomicAdd(ar + 5,  b4.y);
        atomicAdd(ar + 6,  b4.z);
        atomicAdd(ar + 7,  b4.w);
        atomicAdd(ar + 8,  c.x);
        atomicAdd(ar + 9,  c.y);
        atomicAdd(ar + 10, c.z);
        atomicAdd(ar + 11, c.w);
        atomicAdd(&cnt[loc], 1.f);
    }
    __syncthreads();

    int node = b * SSZ + t;
    if (t < SSZ && node < N_NODES) {
        float inv = 1.f / fmaxf(cnt[t], 1.f);
        float m[D], xi[D];
        const float* ar = &agg[t * D];
#pragma unroll
        for (int d = 0; d < D; ++d) m[d] = ar[d] * inv;
        const float4* xr = (const float4*)(x + (size_t)node * D);
        float4 x0 = xr[0], x1 = xr[1], x2 = xr[2];
        xi[0] = x0.x; xi[1] = x0.y; xi[2]  = x0.z; xi[3]  = x0.w;
        xi[4] = x1.x; xi[5] = x1.y; xi[6]  = x1.z; xi[7]  = x1.w;
        xi[8] = x2.x; xi[9] = x2.y; xi[10] = x2.z; xi[11] = x2.w;

        float o[D];
#pragma unroll
        for (int oo = 0; oo < D; ++oo) {
            float acc = sb[oo];
#pragma unroll
            for (int d = 0; d < D; ++d) {
                acc += m[d] * sWl[oo * D + d];
                acc += xi[d] * sWr[oo * D + d];
            }
            o[oo] = acc;
        }
        float4* orow = (float4*)(out + (size_t)node * D);
        orow[0] = make_float4(o[0], o[1], o[2], o[3]);
        orow[1] = make_float4(o[4], o[5], o[6], o[7]);
        orow[2] = make_float4(o[8], o[9], o[10], o[11]);
    }
}

// ---------------- Fallback path (round-1): global atomics -------------------

__global__ __launch_bounds__(256) void scatter_kernel(
    const int* __restrict__ ei, const float* __restrict__ x,
    float* __restrict__ agg, float* __restrict__ cnt)
{
    int e = blockIdx.x * blockDim.x + threadIdx.x;
    if (e >= N_EDGES) return;
    int src = ei[e];
    int dst = ei[N_EDGES + e];
    const float4* xr = (const float4*)(x + (size_t)src * D);
    float4 a = xr[0], b4 = xr[1], c = xr[2];
    float* dr = agg + (size_t)dst * D;
    atomicAdd(dr + 0,  a.x);  atomicAdd(dr + 1,  a.y);
    atomicAdd(dr + 2,  a.z);  atomicAdd(dr + 3,  a.w);
    atomicAdd(dr + 4,  b4.x); atomicAdd(dr + 5,  b4.y);
    atomicAdd(dr + 6,  b4.z); atomicAdd(dr + 7,  b4.w);
    atomicAdd(dr + 8,  c.x);  atomicAdd(dr + 9,  c.y);
    atomicAdd(dr + 10, c.z);  atomicAdd(dr + 11, c.w);
    atomicAdd(cnt + dst, 1.0f);
}

__global__ __launch_bounds__(256) void finalize_kernel(
    const float* __restrict__ x, const float* __restrict__ Wl,
    const float* __restrict__ Wr, const float* __restrict__ bias,
    const float* __restrict__ agg, const float* __restrict__ cnt,
    float* __restrict__ out)
{
    __shared__ float sWl[D * D], sWr[D * D], sb[D];
    int t = threadIdx.x;
    if (t < D * D) { sWl[t] = Wl[t]; sWr[t] = Wr[t]; }
    if (t < D) sb[t] = bias[t];
    __syncthreads();
    int i = blockIdx.x * blockDim.x + t;
    if (i >= N_NODES) return;
    float inv = 1.0f / fmaxf(cnt[i], 1.0f);
    float m[D], xi[D];
    const float4* ar = (const float4*)(agg + (size_t)i * D);
    const float4* xr = (const float4*)(x + (size_t)i * D);
    float4 a0 = ar[0], a1 = ar[1], a2 = ar[2];
    float4 x0 = xr[0], x1 = xr[1], x2 = xr[2];
    m[0] = a0.x * inv; m[1] = a0.y * inv; m[2]  = a0.z * inv; m[3]  = a0.w * inv;
    m[4] = a1.x * inv; m[5] = a1.y * inv; m[6]  = a1.z * inv; m[7]  = a1.w * inv;
    m[8] = a2.x * inv; m[9] = a2.y * inv; m[10] = a2.z * inv; m[11] = a2.w * inv;
    xi[0] = x0.x; xi[1] = x0.y; xi[2]  = x0.z; xi[3]  = x0.w;
    xi[4] = x1.x; xi[5] = x1.y; xi[6]  = x1.z; xi[7]  = x1.w;
    xi[8] = x2.x; xi[9] = x2.y; xi[10] = x2.z; xi[11] = x2.w;
    float o[D];
#pragma unroll
    for (int oo = 0; oo < D; ++oo) {
        float acc = sb[oo];
#pragma unroll
        for (int d = 0; d < D; ++d) {
            acc += m[d] * sWl[oo * D + d];
            acc += xi[d] * sWr[oo * D + d];
        }
        o[oo] = acc;
    }
    float4* orow = (float4*)(out + (size_t)i * D);
    orow[0] = make_float4(o[0], o[1], o[2], o[3]);
    orow[1] = make_float4(o[4], o[5], o[6], o[7]);
    orow[2] = make_float4(o[8], o[9], o[10], o[11]);
}

extern "C" void kernel_launch(void* const* d_in, const int* in_sizes, int n_in,
                              void* d_out, int out_size, void* d_ws, size_t ws_size,
                              hipStream_t stream) {
    const float* x    = (const float*)d_in[0];
    const float* Wl   = (const float*)d_in[1];
    const float* Wr   = (const float*)d_in[2];
    const float* bias = (const float*)d_in[3];
    const int*   ei   = (const int*)d_in[4];
    float* out = (float*)d_out;

    size_t sortedBytes = (size_t)N_EDGES * sizeof(unsigned int);        // 25.6 MB
    size_t histBytes   = (size_t)NBLK * NB * sizeof(int);               // 400 KB
    size_t needed = sortedBytes + 2 * histBytes;

    if (ws_size >= needed) {
        unsigned int* sorted = (unsigned int*)d_ws;
        int* hist = (int*)((char*)d_ws + sortedBytes);
        int* off  = (int*)((char*)d_ws + sortedBytes + histBytes);

        hist_kernel<<<NBLK, 256, 0, stream>>>(ei, hist);
        scan_kernel<<<1, 1024, 0, stream>>>(hist, off);
        scatter_sort_kernel<<<NBLK, 256, 0, stream>>>(ei, off, sorted);
        agg_finalize_kernel<<<NB, 256, 0, stream>>>(sorted, off, x, Wl, Wr, bias, out);
    } else {
        float* agg = (float*)d_ws;
        float* cnt = agg + (size_t)N_NODES * D;
        hipMemsetAsync(d_ws, 0, ((size_t)N_NODES * D + N_NODES) * sizeof(float), stream);
        scatter_kernel<<<(N_EDGES + 255) / 256, 256, 0, stream>>>(ei, x, agg, cnt);
        finalize_kernel<<<(N_NODES + 255) / 256, 256, 0, stream>>>(x, Wl, Wr, bias, agg, cnt, out);
    }
}

// Round 4
// 713.216 us; speedup vs baseline: 5.9533x; 1.1754x over previous
//
#include <hip/hip_runtime.h>

#define N_NODES 100000
#define N_EDGES 6400000
#define D 12

#define SLOG 5
#define SSZ  32                            // nodes per bucket
#define NB   ((N_NODES + SSZ - 1) / SSZ)   // 3125 buckets
#define NBLK 512                           // hist/scatter blocks
#define EPB  ((N_EDGES + NBLK - 1) / NBLK) // 12500 edges per block
#define RSTR 13                            // padded agg row stride (odd -> conflict-free)

// ---------------- Fast path: bucket sort by dst>>5, LDS aggregation ---------

// Pass 1: per-block LDS histogram of dst buckets -> global atomic accumulate.
__global__ __launch_bounds__(256) void hist_kernel(
    const int* __restrict__ ei, int* __restrict__ bins)
{
    __shared__ int h[NB];
    for (int i = threadIdx.x; i < NB; i += 256) h[i] = 0;
    __syncthreads();
    int start = blockIdx.x * EPB;
    int end = min(start + EPB, N_EDGES);
    for (int e = start + (int)threadIdx.x; e < end; e += 256) {
        int dst = ei[N_EDGES + e];
        atomicAdd(&h[dst >> SLOG], 1);
    }
    __syncthreads();
    for (int i = threadIdx.x; i < NB; i += 256) {
        int c = h[i];
        if (c) atomicAdd(&bins[i], c);
    }
}

// Pass 2: single block. Exclusive scan of bins -> base[] and cursor[].
__global__ __launch_bounds__(1024) void scan_kernel(
    const int* __restrict__ bins, int* __restrict__ base, int* __restrict__ cursor)
{
    __shared__ int buf[1024];
    __shared__ int carry;
    int tid = threadIdx.x;
    if (tid == 0) carry = 0;
    __syncthreads();
    for (int c0 = 0; c0 < NB; c0 += 1024) {
        int i = c0 + tid;
        int v = (i < NB) ? bins[i] : 0;
        buf[tid] = v;
        __syncthreads();
        for (int o = 1; o < 1024; o <<= 1) {
            int t = (tid >= o) ? buf[tid - o] : 0;
            __syncthreads();
            buf[tid] += t;
            __syncthreads();
        }
        int excl = buf[tid] - v + carry;
        if (i < NB) { base[i] = excl; cursor[i] = excl; }
        __syncthreads();
        if (tid == 0) carry += buf[1023];
        __syncthreads();
    }
    if (tid == 0) base[NB] = N_EDGES;
}

// Pass 3: two LDS passes per block — local hist, reserve packed ranges via one
// global atomic per (block,bin), then scatter edges into sorted[].
__global__ __launch_bounds__(256) void scatter_sort_kernel(
    const int* __restrict__ ei, int* __restrict__ cursor,
    unsigned int* __restrict__ sorted)
{
    __shared__ int h[NB];
    for (int i = threadIdx.x; i < NB; i += 256) h[i] = 0;
    __syncthreads();
    int start = blockIdx.x * EPB;
    int end = min(start + EPB, N_EDGES);
    // local counts
    for (int e = start + (int)threadIdx.x; e < end; e += 256) {
        int dst = ei[N_EDGES + e];
        atomicAdd(&h[dst >> SLOG], 1);
    }
    __syncthreads();
    // reserve ranges: h[bin] becomes this block's write cursor for bin
    for (int i = threadIdx.x; i < NB; i += 256) {
        int c = h[i];
        h[i] = c ? atomicAdd(&cursor[i], c) : 0;
    }
    __syncthreads();
    // scatter
    for (int e = start + (int)threadIdx.x; e < end; e += 256) {
        int src = ei[e];
        int dst = ei[N_EDGES + e];
        int bin = dst >> SLOG;
        int pos = atomicAdd(&h[bin], 1);
        sorted[pos] = ((unsigned)src << SLOG) | (unsigned)(dst & (SSZ - 1));
    }
}

// Pass 4: one block per bucket (32 nodes). LDS-aggregate (stride-13 rows,
// count in col 12), then fused finalize:
// out = (agg/max(cnt,1)) @ Wl^T + x @ Wr^T + b.
__global__ __launch_bounds__(256) void agg_finalize_kernel(
    const unsigned int* __restrict__ sorted, const int* __restrict__ base,
    const float* __restrict__ x, const float* __restrict__ Wl,
    const float* __restrict__ Wr, const float* __restrict__ bias,
    float* __restrict__ out)
{
    __shared__ float agg[SSZ * RSTR];
    __shared__ float sWl[D * D], sWr[D * D], sb[D];
    int t = threadIdx.x;
    int b = blockIdx.x;

    // NOTE: SSZ*RSTR = 416 > 256 threads — MUST be a strided loop (round-3 bug).
    for (int i = t; i < SSZ * RSTR; i += 256) agg[i] = 0.f;
    if (t < D * D) { sWl[t] = Wl[t]; sWr[t] = Wr[t]; }
    if (t < D) sb[t] = bias[t];
    __syncthreads();

    int start = base[b];
    int end = base[b + 1];
    for (int e = start + t; e < end; e += 256) {
        unsigned p = sorted[e];
        int src = (int)(p >> SLOG);
        int loc = (int)(p & (SSZ - 1));
        const float4* xr = (const float4*)(x) + (size_t)src * 3;
        float4 a = xr[0], b4 = xr[1], c = xr[2];
        float* ar = &agg[loc * RSTR];
        atomicAdd(ar + 0,  a.x);
        atomicAdd(ar + 1,  a.y);
        atomicAdd(ar + 2,  a.z);
        atomicAdd(ar + 3,  a.w);
        atomicAdd(ar + 4,  b4.x);
        atomicAdd(ar + 5,  b4.y);
        atomicAdd(ar + 6,  b4.z);
        atomicAdd(ar + 7,  b4.w);
        atomicAdd(ar + 8,  c.x);
        atomicAdd(ar + 9,  c.y);
        atomicAdd(ar + 10, c.z);
        atomicAdd(ar + 11, c.w);
        atomicAdd(ar + 12, 1.f);
    }
    __syncthreads();

    if (t < SSZ) {
        int node = b * SSZ + t;   // 3125*32 == 100000 exactly
        const float* ar = &agg[t * RSTR];
        float inv = 1.f / fmaxf(ar[12], 1.f);
        float m[D], xi[D];
#pragma unroll
        for (int d = 0; d < D; ++d) m[d] = ar[d] * inv;
        const float4* xr = (const float4*)(x) + (size_t)node * 3;
        float4 x0 = xr[0], x1 = xr[1], x2 = xr[2];
        xi[0] = x0.x; xi[1] = x0.y; xi[2]  = x0.z; xi[3]  = x0.w;
        xi[4] = x1.x; xi[5] = x1.y; xi[6]  = x1.z; xi[7]  = x1.w;
        xi[8] = x2.x; xi[9] = x2.y; xi[10] = x2.z; xi[11] = x2.w;

        float o[D];
#pragma unroll
        for (int oo = 0; oo < D; ++oo) {
            float acc = sb[oo];
#pragma unroll
            for (int d = 0; d < D; ++d) {
                acc += m[d] * sWl[oo * D + d];
                acc += xi[d] * sWr[oo * D + d];
            }
            o[oo] = acc;
        }
        float4* orow = (float4*)(out) + (size_t)node * 3;
        orow[0] = make_float4(o[0], o[1], o[2], o[3]);
        orow[1] = make_float4(o[4], o[5], o[6], o[7]);
        orow[2] = make_float4(o[8], o[9], o[10], o[11]);
    }
}

// ---------------- Fallback path: global atomics -----------------------------

__global__ __launch_bounds__(256) void scatter_kernel(
    const int* __restrict__ ei, const float* __restrict__ x,
    float* __restrict__ agg, float* __restrict__ cnt)
{
    int e = blockIdx.x * blockDim.x + threadIdx.x;
    if (e >= N_EDGES) return;
    int src = ei[e];
    int dst = ei[N_EDGES + e];
    const float4* xr = (const float4*)(x + (size_t)src * D);
    float4 a = xr[0], b4 = xr[1], c = xr[2];
    float* dr = agg + (size_t)dst * D;
    atomicAdd(dr + 0,  a.x);  atomicAdd(dr + 1,  a.y);
    atomicAdd(dr + 2,  a.z);  atomicAdd(dr + 3,  a.w);
    atomicAdd(dr + 4,  b4.x); atomicAdd(dr + 5,  b4.y);
    atomicAdd(dr + 6,  b4.z); atomicAdd(dr + 7,  b4.w);
    atomicAdd(dr + 8,  c.x);  atomicAdd(dr + 9,  c.y);
    atomicAdd(dr + 10, c.z);  atomicAdd(dr + 11, c.w);
    atomicAdd(cnt + dst, 1.0f);
}

__global__ __launch_bounds__(256) void finalize_kernel(
    const float* __restrict__ x, const float* __restrict__ Wl,
    const float* __restrict__ Wr, const float* __restrict__ bias,
    const float* __restrict__ agg, const float* __restrict__ cnt,
    float* __restrict__ out)
{
    __shared__ float sWl[D * D], sWr[D * D], sb[D];
    int t = threadIdx.x;
    if (t < D * D) { sWl[t] = Wl[t]; sWr[t] = Wr[t]; }
    if (t < D) sb[t] = bias[t];
    __syncthreads();
    int i = blockIdx.x * blockDim.x + t;
    if (i >= N_NODES) return;
    float inv = 1.0f / fmaxf(cnt[i], 1.0f);
    float m[D], xi[D];
    const float4* ar = (const float4*)(agg + (size_t)i * D);
    const float4* xr = (const float4*)(x + (size_t)i * D);
    float4 a0 = ar[0], a1 = ar[1], a2 = ar[2];
    float4 x0 = xr[0], x1 = xr[1], x2 = xr[2];
    m[0] = a0.x * inv; m[1] = a0.y * inv; m[2]  = a0.z * inv; m[3]  = a0.w * inv;
    m[4] = a1.x * inv; m[5] = a1.y * inv; m[6]  = a1.z * inv; m[7]  = a1.w * inv;
    m[8] = a2.x * inv; m[9] = a2.y * inv; m[10] = a2.z * inv; m[11] = a2.w * inv;
    xi[0] = x0.x; xi[1] = x0.y; xi[2]  = x0.z; xi[3]  = x0.w;
    xi[4] = x1.x; xi[5] = x1.y; xi[6]  = x1.z; xi[7]  = x1.w;
    xi[8] = x2.x; xi[9] = x2.y; xi[10] = x2.z; xi[11] = x2.w;
    float o[D];
#pragma unroll
    for (int oo = 0; oo < D; ++oo) {
        float acc = sb[oo];
#pragma unroll
        for (int d = 0; d < D; ++d) {
            acc += m[d] * sWl[oo * D + d];
            acc += xi[d] * sWr[oo * D + d];
        }
        o[oo] = acc;
    }
    float4* orow = (float4*)(out + (size_t)i * D);
    orow[0] = make_float4(o[0], o[1], o[2], o[3]);
    orow[1] = make_float4(o[4], o[5], o[6], o[7]);
    orow[2] = make_float4(o[8], o[9], o[10], o[11]);
}

extern "C" void kernel_launch(void* const* d_in, const int* in_sizes, int n_in,
                              void* d_out, int out_size, void* d_ws, size_t ws_size,
                              hipStream_t stream) {
    const float* x    = (const float*)d_in[0];
    const float* Wl   = (const float*)d_in[1];
    const float* Wr   = (const float*)d_in[2];
    const float* bias = (const float*)d_in[3];
    const int*   ei   = (const int*)d_in[4];
    float* out = (float*)d_out;

    size_t sortedBytes = (size_t)N_EDGES * sizeof(unsigned int);   // 25.6 MB
    size_t binsBytes   = (size_t)NB * sizeof(int);
    size_t baseBytes   = (size_t)(NB + 1) * sizeof(int);
    size_t needed = sortedBytes + binsBytes + baseBytes + binsBytes;

    if (ws_size >= needed) {
        char* p = (char*)d_ws;
        unsigned int* sorted = (unsigned int*)p;        p += sortedBytes;
        int* bins   = (int*)p;                          p += binsBytes;
        int* base   = (int*)p;                          p += baseBytes;
        int* cursor = (int*)p;

        hipMemsetAsync(bins, 0, binsBytes, stream);
        hist_kernel<<<NBLK, 256, 0, stream>>>(ei, bins);
        scan_kernel<<<1, 1024, 0, stream>>>(bins, base, cursor);
        scatter_sort_kernel<<<NBLK, 256, 0, stream>>>(ei, cursor, sorted);
        agg_finalize_kernel<<<NB, 256, 0, stream>>>(sorted, base, x, Wl, Wr, bias, out);
    } else {
        float* agg = (float*)d_ws;
        float* cnt = agg + (size_t)N_NODES * D;
        hipMemsetAsync(d_ws, 0, ((size_t)N_NODES * D + N_NODES) * sizeof(float), stream);
        scatter_kernel<<<(N_EDGES + 255) / 256, 256, 0, stream>>>(ei, x, agg, cnt);
        finalize_kernel<<<(N_NODES + 255) / 256, 256, 0, stream>>>(x, Wl, Wr, bias, agg, cnt, out);
    }
}

// Round 5
// 706.432 us; speedup vs baseline: 6.0105x; 1.0096x over previous
//
#include <hip/hip_runtime.h>

#define N_NODES 100000
#define N_EDGES 6400000
#define D 12

#define SLOG 5
#define SSZ  32                            // nodes per bucket
#define NB   ((N_NODES + SSZ - 1) / SSZ)   // 3125 buckets
#define NBLK 512                           // hist/scatter blocks
#define EPB  ((N_EDGES + NBLK - 1) / NBLK) // 12500 edges per block
#define RSTR 13                            // padded agg row stride (odd -> conflict-free)

// ---- bf16 helpers ----------------------------------------------------------
__device__ __forceinline__ unsigned int f2bf(float f) {
    unsigned int u = __float_as_uint(f);
    return (u + 0x7fffu + ((u >> 16) & 1u)) >> 16;   // RTNE
}
__device__ __forceinline__ unsigned int pk2(float lo, float hi) {
    return (f2bf(hi) << 16) | f2bf(lo);
}
__device__ __forceinline__ float bflo(unsigned int u) { return __uint_as_float(u << 16); }
__device__ __forceinline__ float bfhi(unsigned int u) { return __uint_as_float(u & 0xffff0000u); }

// Prep: fp32 x [N,12] -> bf16 xb padded rows of 16 elems (32 B, 3.2 MB total).
__global__ __launch_bounds__(256) void prep_kernel(
    const float* __restrict__ x, unsigned int* __restrict__ xb)
{
    int i = blockIdx.x * 256 + threadIdx.x;
    if (i >= N_NODES) return;
    const float4* xr = (const float4*)(x) + (size_t)i * 3;
    float4 a = xr[0], b = xr[1], c = xr[2];
    unsigned int* o = xb + (size_t)i * 8;
    ((uint4*)o)[0] = make_uint4(pk2(a.x, a.y), pk2(a.z, a.w), pk2(b.x, b.y), pk2(b.z, b.w));
    ((uint2*)(o + 4))[0] = make_uint2(pk2(c.x, c.y), pk2(c.z, c.w));
}

// ---------------- Fast path: bucket sort by dst>>5, LDS aggregation ---------

// Pass 1: per-block LDS histogram (4-edge batched reads) -> global atomics.
__global__ __launch_bounds__(256) void hist_kernel(
    const int* __restrict__ ei, int* __restrict__ bins)
{
    __shared__ int h[NB];
    for (int i = threadIdx.x; i < NB; i += 256) h[i] = 0;
    __syncthreads();
    const int* dei = ei + N_EDGES;
    int start = blockIdx.x * EPB;
    int end = min(start + EPB, N_EDGES);
    int e = start + (int)threadIdx.x;
    while (e + 768 < end) {
        int d0 = dei[e], d1 = dei[e + 256], d2 = dei[e + 512], d3 = dei[e + 768];
        atomicAdd(&h[d0 >> SLOG], 1);
        atomicAdd(&h[d1 >> SLOG], 1);
        atomicAdd(&h[d2 >> SLOG], 1);
        atomicAdd(&h[d3 >> SLOG], 1);
        e += 1024;
    }
    while (e < end) { atomicAdd(&h[dei[e] >> SLOG], 1); e += 256; }
    __syncthreads();
    for (int i = threadIdx.x; i < NB; i += 256) {
        int c = h[i];
        if (c) atomicAdd(&bins[i], c);
    }
}

// Pass 2: single block. Exclusive scan of bins -> base[] and cursor[].
__global__ __launch_bounds__(1024) void scan_kernel(
    const int* __restrict__ bins, int* __restrict__ base, int* __restrict__ cursor)
{
    __shared__ int buf[1024];
    __shared__ int carry;
    int tid = threadIdx.x;
    if (tid == 0) carry = 0;
    __syncthreads();
    for (int c0 = 0; c0 < NB; c0 += 1024) {
        int i = c0 + tid;
        int v = (i < NB) ? bins[i] : 0;
        buf[tid] = v;
        __syncthreads();
        for (int o = 1; o < 1024; o <<= 1) {
            int t = (tid >= o) ? buf[tid - o] : 0;
            __syncthreads();
            buf[tid] += t;
            __syncthreads();
        }
        int excl = buf[tid] - v + carry;
        if (i < NB) { base[i] = excl; cursor[i] = excl; }
        __syncthreads();
        if (tid == 0) carry += buf[1023];
        __syncthreads();
    }
    if (tid == 0) base[NB] = N_EDGES;
}

// Pass 3: local hist -> reserve packed ranges (1 global atomic/(block,bin)) ->
// scatter packed (src<<5 | dst&31), 4-edge batched.
__global__ __launch_bounds__(256) void scatter_sort_kernel(
    const int* __restrict__ ei, int* __restrict__ cursor,
    unsigned int* __restrict__ sorted)
{
    __shared__ int h[NB];
    for (int i = threadIdx.x; i < NB; i += 256) h[i] = 0;
    __syncthreads();
    const int* dei = ei + N_EDGES;
    int start = blockIdx.x * EPB;
    int end = min(start + EPB, N_EDGES);
    int e = start + (int)threadIdx.x;
    while (e + 768 < end) {
        int d0 = dei[e], d1 = dei[e + 256], d2 = dei[e + 512], d3 = dei[e + 768];
        atomicAdd(&h[d0 >> SLOG], 1);
        atomicAdd(&h[d1 >> SLOG], 1);
        atomicAdd(&h[d2 >> SLOG], 1);
        atomicAdd(&h[d3 >> SLOG], 1);
        e += 1024;
    }
    while (e < end) { atomicAdd(&h[dei[e] >> SLOG], 1); e += 256; }
    __syncthreads();
    for (int i = threadIdx.x; i < NB; i += 256) {
        int c = h[i];
        h[i] = c ? atomicAdd(&cursor[i], c) : 0;
    }
    __syncthreads();
    e = start + (int)threadIdx.x;
    while (e + 768 < end) {
        int s0 = ei[e], s1 = ei[e + 256], s2 = ei[e + 512], s3 = ei[e + 768];
        int d0 = dei[e], d1 = dei[e + 256], d2 = dei[e + 512], d3 = dei[e + 768];
        int p0 = atomicAdd(&h[d0 >> SLOG], 1);
        int p1 = atomicAdd(&h[d1 >> SLOG], 1);
        int p2 = atomicAdd(&h[d2 >> SLOG], 1);
        int p3 = atomicAdd(&h[d3 >> SLOG], 1);
        sorted[p0] = ((unsigned)s0 << SLOG) | (unsigned)(d0 & (SSZ - 1));
        sorted[p1] = ((unsigned)s1 << SLOG) | (unsigned)(d1 & (SSZ - 1));
        sorted[p2] = ((unsigned)s2 << SLOG) | (unsigned)(d2 & (SSZ - 1));
        sorted[p3] = ((unsigned)s3 << SLOG) | (unsigned)(d3 & (SSZ - 1));
        e += 1024;
    }
    while (e < end) {
        int s = ei[e], d = dei[e];
        int pos = atomicAdd(&h[d >> SLOG], 1);
        sorted[pos] = ((unsigned)s << SLOG) | (unsigned)(d & (SSZ - 1));
        e += 256;
    }
}

__device__ __forceinline__ void accum_edge(float* aggp, unsigned p,
                                           uint4 q0, uint2 q1)
{
    float* ar = aggp + (p & (SSZ - 1)) * RSTR;
    atomicAdd(ar + 0,  bflo(q0.x));
    atomicAdd(ar + 1,  bfhi(q0.x));
    atomicAdd(ar + 2,  bflo(q0.y));
    atomicAdd(ar + 3,  bfhi(q0.y));
    atomicAdd(ar + 4,  bflo(q0.z));
    atomicAdd(ar + 5,  bfhi(q0.z));
    atomicAdd(ar + 6,  bflo(q0.w));
    atomicAdd(ar + 7,  bfhi(q0.w));
    atomicAdd(ar + 8,  bflo(q1.x));
    atomicAdd(ar + 9,  bfhi(q1.x));
    atomicAdd(ar + 10, bflo(q1.y));
    atomicAdd(ar + 11, bfhi(q1.y));
    atomicAdd(ar + 12, 1.f);
}

// Pass 4: one block per bucket (32 nodes). bf16 gathers (L2-resident xb),
// 4-edge batching for MLP, LDS fp32 accumulate, fused finalize.
__global__ __launch_bounds__(256, 4) void agg_finalize_kernel(
    const unsigned int* __restrict__ sorted, const int* __restrict__ base,
    const unsigned int* __restrict__ xb,
    const float* __restrict__ x, const float* __restrict__ Wl,
    const float* __restrict__ Wr, const float* __restrict__ bias,
    float* __restrict__ out)
{
    __shared__ float agg[SSZ * RSTR];
    __shared__ float sWl[D * D], sWr[D * D], sb[D];
    int t = threadIdx.x;
    int b = blockIdx.x;

    for (int i = t; i < SSZ * RSTR; i += 256) agg[i] = 0.f;   // 416 > 256: strided!
    if (t < D * D) { sWl[t] = Wl[t]; sWr[t] = Wr[t]; }
    if (t < D) sb[t] = bias[t];
    __syncthreads();

    int start = base[b];
    int end = base[b + 1];
    int e = start + t;
    while (e + 768 < end) {
        unsigned p0 = sorted[e], p1 = sorted[e + 256];
        unsigned p2 = sorted[e + 512], p3 = sorted[e + 768];
        const uint4* r0 = (const uint4*)(xb) + 2 * (size_t)(p0 >> SLOG);
        const uint4* r1 = (const uint4*)(xb) + 2 * (size_t)(p1 >> SLOG);
        const uint4* r2 = (const uint4*)(xb) + 2 * (size_t)(p2 >> SLOG);
        const uint4* r3 = (const uint4*)(xb) + 2 * (size_t)(p3 >> SLOG);
        uint4 a0 = r0[0]; uint2 b0 = ((const uint2*)(r0 + 1))[0];
        uint4 a1 = r1[0]; uint2 b1 = ((const uint2*)(r1 + 1))[0];
        uint4 a2 = r2[0]; uint2 b2 = ((const uint2*)(r2 + 1))[0];
        uint4 a3 = r3[0]; uint2 b3 = ((const uint2*)(r3 + 1))[0];
        accum_edge(agg, p0, a0, b0);
        accum_edge(agg, p1, a1, b1);
        accum_edge(agg, p2, a2, b2);
        accum_edge(agg, p3, a3, b3);
        e += 1024;
    }
    while (e < end) {
        unsigned p = sorted[e];
        const uint4* r = (const uint4*)(xb) + 2 * (size_t)(p >> SLOG);
        uint4 a = r[0]; uint2 bq = ((const uint2*)(r + 1))[0];
        accum_edge(agg, p, a, bq);
        e += 256;
    }
    __syncthreads();

    if (t < SSZ) {
        int node = b * SSZ + t;   // 3125*32 == 100000 exactly
        const float* ar = &agg[t * RSTR];
        float inv = 1.f / fmaxf(ar[12], 1.f);
        float m[D], xi[D];
#pragma unroll
        for (int d = 0; d < D; ++d) m[d] = ar[d] * inv;
        const float4* xr = (const float4*)(x) + (size_t)node * 3;
        float4 x0 = xr[0], x1 = xr[1], x2 = xr[2];
        xi[0] = x0.x; xi[1] = x0.y; xi[2]  = x0.z; xi[3]  = x0.w;
        xi[4] = x1.x; xi[5] = x1.y; xi[6]  = x1.z; xi[7]  = x1.w;
        xi[8] = x2.x; xi[9] = x2.y; xi[10] = x2.z; xi[11] = x2.w;

        float o[D];
#pragma unroll
        for (int oo = 0; oo < D; ++oo) {
            float acc = sb[oo];
#pragma unroll
            for (int d = 0; d < D; ++d) {
                acc += m[d] * sWl[oo * D + d];
                acc += xi[d] * sWr[oo * D + d];
            }
            o[oo] = acc;
        }
        float4* orow = (float4*)(out) + (size_t)node * 3;
        orow[0] = make_float4(o[0], o[1], o[2], o[3]);
        orow[1] = make_float4(o[4], o[5], o[6], o[7]);
        orow[2] = make_float4(o[8], o[9], o[10], o[11]);
    }
}

// Mid-tier agg (fp32 gather, no xb buffer needed) — used if ws is tight.
__global__ __launch_bounds__(256) void agg_finalize_f32_kernel(
    const unsigned int* __restrict__ sorted, const int* __restrict__ base,
    const float* __restrict__ x, const float* __restrict__ Wl,
    const float* __restrict__ Wr, const float* __restrict__ bias,
    float* __restrict__ out)
{
    __shared__ float agg[SSZ * RSTR];
    __shared__ float sWl[D * D], sWr[D * D], sb[D];
    int t = threadIdx.x;
    int b = blockIdx.x;
    for (int i = t; i < SSZ * RSTR; i += 256) agg[i] = 0.f;
    if (t < D * D) { sWl[t] = Wl[t]; sWr[t] = Wr[t]; }
    if (t < D) sb[t] = bias[t];
    __syncthreads();
    int start = base[b];
    int end = base[b + 1];
    for (int e = start + t; e < end; e += 256) {
        unsigned p = sorted[e];
        int src = (int)(p >> SLOG);
        int loc = (int)(p & (SSZ - 1));
        const float4* xr = (const float4*)(x) + (size_t)src * 3;
        float4 a = xr[0], b4 = xr[1], c = xr[2];
        float* ar = &agg[loc * RSTR];
        atomicAdd(ar + 0,  a.x);  atomicAdd(ar + 1,  a.y);
        atomicAdd(ar + 2,  a.z);  atomicAdd(ar + 3,  a.w);
        atomicAdd(ar + 4,  b4.x); atomicAdd(ar + 5,  b4.y);
        atomicAdd(ar + 6,  b4.z); atomicAdd(ar + 7,  b4.w);
        atomicAdd(ar + 8,  c.x);  atomicAdd(ar + 9,  c.y);
        atomicAdd(ar + 10, c.z);  atomicAdd(ar + 11, c.w);
        atomicAdd(ar + 12, 1.f);
    }
    __syncthreads();
    if (t < SSZ) {
        int node = b * SSZ + t;
        const float* ar = &agg[t * RSTR];
        float inv = 1.f / fmaxf(ar[12], 1.f);
        float m[D], xi[D];
#pragma unroll
        for (int d = 0; d < D; ++d) m[d] = ar[d] * inv;
        const float4* xr = (const float4*)(x) + (size_t)node * 3;
        float4 x0 = xr[0], x1 = xr[1], x2 = xr[2];
        xi[0] = x0.x; xi[1] = x0.y; xi[2]  = x0.z; xi[3]  = x0.w;
        xi[4] = x1.x; xi[5] = x1.y; xi[6]  = x1.z; xi[7]  = x1.w;
        xi[8] = x2.x; xi[9] = x2.y; xi[10] = x2.z; xi[11] = x2.w;
        float o[D];
#pragma unroll
        for (int oo = 0; oo < D; ++oo) {
            float acc = sb[oo];
#pragma unroll
            for (int d = 0; d < D; ++d) {
                acc += m[d] * sWl[oo * D + d];
                acc += xi[d] * sWr[oo * D + d];
            }
            o[oo] = acc;
        }
        float4* orow = (float4*)(out) + (size_t)node * 3;
        orow[0] = make_float4(o[0], o[1], o[2], o[3]);
        orow[1] = make_float4(o[4], o[5], o[6], o[7]);
        orow[2] = make_float4(o[8], o[9], o[10], o[11]);
    }
}

// ---------------- Last-resort fallback: global atomics ----------------------

__global__ __launch_bounds__(256) void scatter_kernel(
    const int* __restrict__ ei, const float* __restrict__ x,
    float* __restrict__ agg, float* __restrict__ cnt)
{
    int e = blockIdx.x * blockDim.x + threadIdx.x;
    if (e >= N_EDGES) return;
    int src = ei[e];
    int dst = ei[N_EDGES + e];
    const float4* xr = (const float4*)(x + (size_t)src * D);
    float4 a = xr[0], b4 = xr[1], c = xr[2];
    float* dr = agg + (size_t)dst * D;
    atomicAdd(dr + 0,  a.x);  atomicAdd(dr + 1,  a.y);
    atomicAdd(dr + 2,  a.z);  atomicAdd(dr + 3,  a.w);
    atomicAdd(dr + 4,  b4.x); atomicAdd(dr + 5,  b4.y);
    atomicAdd(dr + 6,  b4.z); atomicAdd(dr + 7,  b4.w);
    atomicAdd(dr + 8,  c.x);  atomicAdd(dr + 9,  c.y);
    atomicAdd(dr + 10, c.z);  atomicAdd(dr + 11, c.w);
    atomicAdd(cnt + dst, 1.0f);
}

__global__ __launch_bounds__(256) void finalize_kernel(
    const float* __restrict__ x, const float* __restrict__ Wl,
    const float* __restrict__ Wr, const float* __restrict__ bias,
    const float* __restrict__ agg, const float* __restrict__ cnt,
    float* __restrict__ out)
{
    __shared__ float sWl[D * D], sWr[D * D], sb[D];
    int t = threadIdx.x;
    if (t < D * D) { sWl[t] = Wl[t]; sWr[t] = Wr[t]; }
    if (t < D) sb[t] = bias[t];
    __syncthreads();
    int i = blockIdx.x * blockDim.x + t;
    if (i >= N_NODES) return;
    float inv = 1.0f / fmaxf(cnt[i], 1.0f);
    float m[D], xi[D];
    const float4* ar = (const float4*)(agg + (size_t)i * D);
    const float4* xr = (const float4*)(x + (size_t)i * D);
    float4 a0 = ar[0], a1 = ar[1], a2 = ar[2];
    float4 x0 = xr[0], x1 = xr[1], x2 = xr[2];
    m[0] = a0.x * inv; m[1] = a0.y * inv; m[2]  = a0.z * inv; m[3]  = a0.w * inv;
    m[4] = a1.x * inv; m[5] = a1.y * inv; m[6]  = a1.z * inv; m[7]  = a1.w * inv;
    m[8] = a2.x * inv; m[9] = a2.y * inv; m[10] = a2.z * inv; m[11] = a2.w * inv;
    xi[0] = x0.x; xi[1] = x0.y; xi[2]  = x0.z; xi[3]  = x0.w;
    xi[4] = x1.x; xi[5] = x1.y; xi[6]  = x1.z; xi[7]  = x1.w;
    xi[8] = x2.x; xi[9] = x2.y; xi[10] = x2.z; xi[11] = x2.w;
    float o[D];
#pragma unroll
    for (int oo = 0; oo < D; ++oo) {
        float acc = sb[oo];
#pragma unroll
        for (int d = 0; d < D; ++d) {
            acc += m[d] * sWl[oo * D + d];
            acc += xi[d] * sWr[oo * D + d];
        }
        o[oo] = acc;
    }
    float4* orow = (float4*)(out + (size_t)i * D);
    orow[0] = make_float4(o[0], o[1], o[2], o[3]);
    orow[1] = make_float4(o[4], o[5], o[6], o[7]);
    orow[2] = make_float4(o[8], o[9], o[10], o[11]);
}

extern "C" void kernel_launch(void* const* d_in, const int* in_sizes, int n_in,
                              void* d_out, int out_size, void* d_ws, size_t ws_size,
                              hipStream_t stream) {
    const float* x    = (const float*)d_in[0];
    const float* Wl   = (const float*)d_in[1];
    const float* Wr   = (const float*)d_in[2];
    const float* bias = (const float*)d_in[3];
    const int*   ei   = (const int*)d_in[4];
    float* out = (float*)d_out;

    size_t sortedBytes = (size_t)N_EDGES * sizeof(unsigned int);   // 25.6 MB
    size_t xbBytes     = (size_t)N_NODES * 8 * sizeof(unsigned int); // 3.2 MB
    size_t binsBytes   = (size_t)NB * sizeof(int);
    size_t baseBytes   = (size_t)(NB + 1) * sizeof(int);
    size_t neededFull = sortedBytes + xbBytes + binsBytes + baseBytes + binsBytes;
    size_t neededMid  = sortedBytes + binsBytes + baseBytes + binsBytes;

    if (ws_size >= neededFull) {
        char* p = (char*)d_ws;
        unsigned int* sorted = (unsigned int*)p;        p += sortedBytes;
        unsigned int* xb     = (unsigned int*)p;        p += xbBytes;
        int* bins   = (int*)p;                          p += binsBytes;
        int* base   = (int*)p;                          p += baseBytes;
        int* cursor = (int*)p;

        hipMemsetAsync(bins, 0, binsBytes, stream);
        prep_kernel<<<(N_NODES + 255) / 256, 256, 0, stream>>>(x, xb);
        hist_kernel<<<NBLK, 256, 0, stream>>>(ei, bins);
        scan_kernel<<<1, 1024, 0, stream>>>(bins, base, cursor);
        scatter_sort_kernel<<<NBLK, 256, 0, stream>>>(ei, cursor, sorted);
        agg_finalize_kernel<<<NB, 256, 0, stream>>>(sorted, base, xb, x, Wl, Wr, bias, out);
    } else if (ws_size >= neededMid) {
        char* p = (char*)d_ws;
        unsigned int* sorted = (unsigned int*)p;        p += sortedBytes;
        int* bins   = (int*)p;                          p += binsBytes;
        int* base   = (int*)p;                          p += baseBytes;
        int* cursor = (int*)p;

        hipMemsetAsync(bins, 0, binsBytes, stream);
        hist_kernel<<<NBLK, 256, 0, stream>>>(ei, bins);
        scan_kernel<<<1, 1024, 0, stream>>>(bins, base, cursor);
        scatter_sort_kernel<<<NBLK, 256, 0, stream>>>(ei, cursor, sorted);
        agg_finalize_f32_kernel<<<NB, 256, 0, stream>>>(sorted, base, x, Wl, Wr, bias, out);
    } else {
        float* agg = (float*)d_ws;
        float* cnt = agg + (size_t)N_NODES * D;
        hipMemsetAsync(d_ws, 0, ((size_t)N_NODES * D + N_NODES) * sizeof(float), stream);
        scatter_kernel<<<(N_EDGES + 255) / 256, 256, 0, stream>>>(ei, x, agg, cnt);
        finalize_kernel<<<(N_NODES + 255) / 256, 256, 0, stream>>>(x, Wl, Wr, bias, agg, cnt, out);
    }
}

// Round 6
// 304.798 us; speedup vs baseline: 13.9305x; 2.3177x over previous
//
#include <hip/hip_runtime.h>

#define N_NODES 100000
#define N_EDGES 6400000
#define D 12

#define SLOG 5
#define SSZ  32                            // nodes per bucket
#define NB   ((N_NODES + SSZ - 1) / SSZ)   // 3125 buckets
#define NBLK 512                           // hist/scatter blocks
#define EPB  ((N_EDGES + NBLK - 1) / NBLK) // 12500 edges per block
#define RSTR 13                            // fallback agg row stride

#define CAP  1280                          // edges per chunk in pass 4
#define EPT  (CAP / 256)                   // 5 edges per thread per chunk

// ---- bf16 helpers ----------------------------------------------------------
__device__ __forceinline__ unsigned int f2bf(float f) {
    unsigned int u = __float_as_uint(f);
    return (u + 0x7fffu + ((u >> 16) & 1u)) >> 16;   // RTNE
}
__device__ __forceinline__ unsigned int pk2(float lo, float hi) {
    return (f2bf(hi) << 16) | f2bf(lo);
}
__device__ __forceinline__ float bflo(unsigned int u) { return __uint_as_float(u << 16); }
__device__ __forceinline__ float bfhi(unsigned int u) { return __uint_as_float(u & 0xffff0000u); }

// Prep: fp32 x [N,12] -> bf16 xb padded rows of 16 elems (32 B, 3.2 MB total).
__global__ __launch_bounds__(256) void prep_kernel(
    const float* __restrict__ x, unsigned int* __restrict__ xb)
{
    int i = blockIdx.x * 256 + threadIdx.x;
    if (i >= N_NODES) return;
    const float4* xr = (const float4*)(x) + (size_t)i * 3;
    float4 a = xr[0], b = xr[1], c = xr[2];
    unsigned int* o = xb + (size_t)i * 8;
    ((uint4*)o)[0] = make_uint4(pk2(a.x, a.y), pk2(a.z, a.w), pk2(b.x, b.y), pk2(b.z, b.w));
    ((uint2*)(o + 4))[0] = make_uint2(pk2(c.x, c.y), pk2(c.z, c.w));
}

// Pass 1: per-block LDS histogram (batched reads) -> global atomics.
__global__ __launch_bounds__(256) void hist_kernel(
    const int* __restrict__ ei, int* __restrict__ bins)
{
    __shared__ int h[NB];
    for (int i = threadIdx.x; i < NB; i += 256) h[i] = 0;
    __syncthreads();
    const int* dei = ei + N_EDGES;
    int start = blockIdx.x * EPB;
    int end = min(start + EPB, N_EDGES);
    int e = start + (int)threadIdx.x;
    while (e + 768 < end) {
        int d0 = dei[e], d1 = dei[e + 256], d2 = dei[e + 512], d3 = dei[e + 768];
        atomicAdd(&h[d0 >> SLOG], 1);
        atomicAdd(&h[d1 >> SLOG], 1);
        atomicAdd(&h[d2 >> SLOG], 1);
        atomicAdd(&h[d3 >> SLOG], 1);
        e += 1024;
    }
    while (e < end) { atomicAdd(&h[dei[e] >> SLOG], 1); e += 256; }
    __syncthreads();
    for (int i = threadIdx.x; i < NB; i += 256) {
        int c = h[i];
        if (c) atomicAdd(&bins[i], c);
    }
}

// Pass 2: single block. Exclusive scan of bins -> base[] and cursor[].
__global__ __launch_bounds__(1024) void scan_kernel(
    const int* __restrict__ bins, int* __restrict__ base, int* __restrict__ cursor)
{
    __shared__ int buf[1024];
    __shared__ int carry;
    int tid = threadIdx.x;
    if (tid == 0) carry = 0;
    __syncthreads();
    for (int c0 = 0; c0 < NB; c0 += 1024) {
        int i = c0 + tid;
        int v = (i < NB) ? bins[i] : 0;
        buf[tid] = v;
        __syncthreads();
        for (int o = 1; o < 1024; o <<= 1) {
            int t = (tid >= o) ? buf[tid - o] : 0;
            __syncthreads();
            buf[tid] += t;
            __syncthreads();
        }
        int excl = buf[tid] - v + carry;
        if (i < NB) { base[i] = excl; cursor[i] = excl; }
        __syncthreads();
        if (tid == 0) carry += buf[1023];
        __syncthreads();
    }
    if (tid == 0) base[NB] = N_EDGES;
}

// Pass 3: local hist -> reserve packed ranges -> scatter (src<<5 | dst&31).
__global__ __launch_bounds__(256) void scatter_sort_kernel(
    const int* __restrict__ ei, int* __restrict__ cursor,
    unsigned int* __restrict__ sorted)
{
    __shared__ int h[NB];
    for (int i = threadIdx.x; i < NB; i += 256) h[i] = 0;
    __syncthreads();
    const int* dei = ei + N_EDGES;
    int start = blockIdx.x * EPB;
    int end = min(start + EPB, N_EDGES);
    int e = start + (int)threadIdx.x;
    while (e + 768 < end) {
        int d0 = dei[e], d1 = dei[e + 256], d2 = dei[e + 512], d3 = dei[e + 768];
        atomicAdd(&h[d0 >> SLOG], 1);
        atomicAdd(&h[d1 >> SLOG], 1);
        atomicAdd(&h[d2 >> SLOG], 1);
        atomicAdd(&h[d3 >> SLOG], 1);
        e += 1024;
    }
    while (e < end) { atomicAdd(&h[dei[e] >> SLOG], 1); e += 256; }
    __syncthreads();
    for (int i = threadIdx.x; i < NB; i += 256) {
        int c = h[i];
        h[i] = c ? atomicAdd(&cursor[i], c) : 0;
    }
    __syncthreads();
    e = start + (int)threadIdx.x;
    while (e + 768 < end) {
        int s0 = ei[e], s1 = ei[e + 256], s2 = ei[e + 512], s3 = ei[e + 768];
        int d0 = dei[e], d1 = dei[e + 256], d2 = dei[e + 512], d3 = dei[e + 768];
        int p0 = atomicAdd(&h[d0 >> SLOG], 1);
        int p1 = atomicAdd(&h[d1 >> SLOG], 1);
        int p2 = atomicAdd(&h[d2 >> SLOG], 1);
        int p3 = atomicAdd(&h[d3 >> SLOG], 1);
        sorted[p0] = ((unsigned)s0 << SLOG) | (unsigned)(d0 & (SSZ - 1));
        sorted[p1] = ((unsigned)s1 << SLOG) | (unsigned)(d1 & (SSZ - 1));
        sorted[p2] = ((unsigned)s2 << SLOG) | (unsigned)(d2 & (SSZ - 1));
        sorted[p3] = ((unsigned)s3 << SLOG) | (unsigned)(d3 & (SSZ - 1));
        e += 1024;
    }
    while (e < end) {
        int s = ei[e], d = dei[e];
        int pos = atomicAdd(&h[d >> SLOG], 1);
        sorted[pos] = ((unsigned)s << SLOG) | (unsigned)(d & (SSZ - 1));
        e += 256;
    }
}

// Pass 4 (rewritten): register accumulation, 2 LDS atomics/edge instead of 13.
// Per chunk: count locs -> segment bases -> place gathered bf16 rows into LDS
// per-node segments -> 8 threads per node accumulate in registers.
__global__ __launch_bounds__(256, 4) void agg_finalize_kernel(
    const unsigned int* __restrict__ sorted, const int* __restrict__ base,
    const unsigned int* __restrict__ xb,
    const float* __restrict__ x, const float* __restrict__ Wl,
    const float* __restrict__ Wr, const float* __restrict__ bias,
    float* __restrict__ out)
{
    __shared__ float sWl[D * D], sWr[D * D], sb[D];
    __shared__ int cnt[SSZ];
    __shared__ int segbase[SSZ + 1];
    __shared__ int cursor[SSZ];
    __shared__ int cnt_tot[SSZ];
    __shared__ unsigned vals[CAP * 6];   // 24 B per edge slot; reused as red[]

    int t = threadIdx.x;
    int b = blockIdx.x;

    if (t < D * D) { sWl[t] = Wl[t]; sWr[t] = Wr[t]; }
    if (t < D) sb[t] = bias[t];
    if (t < SSZ) cnt_tot[t] = 0;

    float acc[D];
#pragma unroll
    for (int d = 0; d < D; ++d) acc[d] = 0.f;

    int loc = t >> 3;       // node owned in phase B
    int sub = t & 7;

    int start = base[b];
    int end = base[b + 1];

    for (int c0 = start; c0 < end; c0 += CAP) {
        int n = min(CAP, end - c0);
        if (t < SSZ) cnt[t] = 0;
        __syncthreads();

        // Load my packed edges into registers (coalesced), then count.
        unsigned pe[EPT];
        int ne = 0;
        for (int j = t; j < n; j += 256) pe[ne++] = sorted[c0 + j];
#pragma unroll
        for (int k = 0; k < EPT; ++k)
            if (k < ne) atomicAdd(&cnt[pe[k] & (SSZ - 1)], 1);
        __syncthreads();

        // Tiny serial scan of 32 counters.
        if (t == 0) {
            int s = 0;
#pragma unroll
            for (int i = 0; i < SSZ; ++i) { segbase[i] = s; s += cnt[i]; }
            segbase[SSZ] = s;
        }
        __syncthreads();
        if (t < SSZ) { cursor[t] = segbase[t]; cnt_tot[t] += cnt[t]; }
        __syncthreads();

        // Place: gather bf16 row, write into this node's LDS segment.
#pragma unroll
        for (int k = 0; k < EPT; ++k) {
            if (k < ne) {
                unsigned p = pe[k];
                int slot = atomicAdd(&cursor[p & (SSZ - 1)], 1);
                const unsigned* r = xb + (size_t)(p >> SLOG) * 8;
                uint2 q0 = ((const uint2*)r)[0];
                uint2 q1 = ((const uint2*)r)[1];
                uint2 q2 = ((const uint2*)r)[2];
                unsigned* vv = &vals[slot * 6];
                ((uint2*)vv)[0] = q0;      // 8B-aligned (24B slots)
                ((uint2*)vv)[1] = q1;
                ((uint2*)vv)[2] = q2;
            }
        }
        __syncthreads();

        // Accumulate: thread (loc, sub) scans its node's segment, registers only.
        int s0 = segbase[loc], s1 = segbase[loc + 1];
        for (int j = s0 + sub; j < s1; j += 8) {
            const unsigned* vv = &vals[j * 6];
            uint2 q0 = ((const uint2*)vv)[0];
            uint2 q1 = ((const uint2*)vv)[1];
            uint2 q2 = ((const uint2*)vv)[2];
            acc[0]  += bflo(q0.x); acc[1]  += bfhi(q0.x);
            acc[2]  += bflo(q0.y); acc[3]  += bfhi(q0.y);
            acc[4]  += bflo(q1.x); acc[5]  += bfhi(q1.x);
            acc[6]  += bflo(q1.y); acc[7]  += bfhi(q1.y);
            acc[8]  += bflo(q2.x); acc[9]  += bfhi(q2.x);
            acc[10] += bflo(q2.y); acc[11] += bfhi(q2.y);
        }
        __syncthreads();   // before next chunk reuses cnt/vals
    }

    // Reduce 8 partials per node via padded LDS overlay (stride 417 & 13:
    // both odd-ish vs 32 banks -> conflict-free).
    float* red = (float*)vals;   // needs 8*417 = 3336 floats <= CAP*6 = 7680
#pragma unroll
    for (int d = 0; d < D; ++d) red[sub * 417 + loc * 13 + d] = acc[d];
    __syncthreads();

    if (t < SSZ) {
        int node = b * SSZ + t;   // 3125*32 == 100000 exactly
        float m[D];
#pragma unroll
        for (int d = 0; d < D; ++d) {
            float s = 0.f;
#pragma unroll
            for (int ss = 0; ss < 8; ++ss) s += red[ss * 417 + t * 13 + d];
            m[d] = s;
        }
        float inv = 1.f / fmaxf((float)cnt_tot[t], 1.f);
#pragma unroll
        for (int d = 0; d < D; ++d) m[d] *= inv;

        float xi[D];
        const float4* xr = (const float4*)(x) + (size_t)node * 3;
        float4 x0 = xr[0], x1 = xr[1], x2 = xr[2];
        xi[0] = x0.x; xi[1] = x0.y; xi[2]  = x0.z; xi[3]  = x0.w;
        xi[4] = x1.x; xi[5] = x1.y; xi[6]  = x1.z; xi[7]  = x1.w;
        xi[8] = x2.x; xi[9] = x2.y; xi[10] = x2.z; xi[11] = x2.w;

        float o[D];
#pragma unroll
        for (int oo = 0; oo < D; ++oo) {
            float a = sb[oo];
#pragma unroll
            for (int d = 0; d < D; ++d) {
                a += m[d] * sWl[oo * D + d];
                a += xi[d] * sWr[oo * D + d];
            }
            o[oo] = a;
        }
        float4* orow = (float4*)(out) + (size_t)node * 3;
        orow[0] = make_float4(o[0], o[1], o[2], o[3]);
        orow[1] = make_float4(o[4], o[5], o[6], o[7]);
        orow[2] = make_float4(o[8], o[9], o[10], o[11]);
    }
}

// Mid-tier agg (fp32 gather + LDS atomics) — used if ws is tight.
__global__ __launch_bounds__(256) void agg_finalize_f32_kernel(
    const unsigned int* __restrict__ sorted, const int* __restrict__ base,
    const float* __restrict__ x, const float* __restrict__ Wl,
    const float* __restrict__ Wr, const float* __restrict__ bias,
    float* __restrict__ out)
{
    __shared__ float agg[SSZ * RSTR];
    __shared__ float sWl[D * D], sWr[D * D], sb[D];
    int t = threadIdx.x;
    int b = blockIdx.x;
    for (int i = t; i < SSZ * RSTR; i += 256) agg[i] = 0.f;
    if (t < D * D) { sWl[t] = Wl[t]; sWr[t] = Wr[t]; }
    if (t < D) sb[t] = bias[t];
    __syncthreads();
    int start = base[b];
    int end = base[b + 1];
    for (int e = start + t; e < end; e += 256) {
        unsigned p = sorted[e];
        int src = (int)(p >> SLOG);
        int lc = (int)(p & (SSZ - 1));
        const float4* xr = (const float4*)(x) + (size_t)src * 3;
        float4 a = xr[0], b4 = xr[1], c = xr[2];
        float* ar = &agg[lc * RSTR];
        atomicAdd(ar + 0,  a.x);  atomicAdd(ar + 1,  a.y);
        atomicAdd(ar + 2,  a.z);  atomicAdd(ar + 3,  a.w);
        atomicAdd(ar + 4,  b4.x); atomicAdd(ar + 5,  b4.y);
        atomicAdd(ar + 6,  b4.z); atomicAdd(ar + 7,  b4.w);
        atomicAdd(ar + 8,  c.x);  atomicAdd(ar + 9,  c.y);
        atomicAdd(ar + 10, c.z);  atomicAdd(ar + 11, c.w);
        atomicAdd(ar + 12, 1.f);
    }
    __syncthreads();
    if (t < SSZ) {
        int node = b * SSZ + t;
        const float* ar = &agg[t * RSTR];
        float inv = 1.f / fmaxf(ar[12], 1.f);
        float m[D], xi[D];
#pragma unroll
        for (int d = 0; d < D; ++d) m[d] = ar[d] * inv;
        const float4* xr = (const float4*)(x) + (size_t)node * 3;
        float4 x0 = xr[0], x1 = xr[1], x2 = xr[2];
        xi[0] = x0.x; xi[1] = x0.y; xi[2]  = x0.z; xi[3]  = x0.w;
        xi[4] = x1.x; xi[5] = x1.y; xi[6]  = x1.z; xi[7]  = x1.w;
        xi[8] = x2.x; xi[9] = x2.y; xi[10] = x2.z; xi[11] = x2.w;
        float o[D];
#pragma unroll
        for (int oo = 0; oo < D; ++oo) {
            float a = sb[oo];
#pragma unroll
            for (int d = 0; d < D; ++d) {
                a += m[d] * sWl[oo * D + d];
                a += xi[d] * sWr[oo * D + d];
            }
            o[oo] = a;
        }
        float4* orow = (float4*)(out) + (size_t)node * 3;
        orow[0] = make_float4(o[0], o[1], o[2], o[3]);
        orow[1] = make_float4(o[4], o[5], o[6], o[7]);
        orow[2] = make_float4(o[8], o[9], o[10], o[11]);
    }
}

// ---------------- Last-resort fallback: global atomics ----------------------

__global__ __launch_bounds__(256) void scatter_kernel(
    const int* __restrict__ ei, const float* __restrict__ x,
    float* __restrict__ agg, float* __restrict__ cnt)
{
    int e = blockIdx.x * blockDim.x + threadIdx.x;
    if (e >= N_EDGES) return;
    int src = ei[e];
    int dst = ei[N_EDGES + e];
    const float4* xr = (const float4*)(x + (size_t)src * D);
    float4 a = xr[0], b4 = xr[1], c = xr[2];
    float* dr = agg + (size_t)dst * D;
    atomicAdd(dr + 0,  a.x);  atomicAdd(dr + 1,  a.y);
    atomicAdd(dr + 2,  a.z);  atomicAdd(dr + 3,  a.w);
    atomicAdd(dr + 4,  b4.x); atomicAdd(dr + 5,  b4.y);
    atomicAdd(dr + 6,  b4.z); atomicAdd(dr + 7,  b4.w);
    atomicAdd(dr + 8,  c.x);  atomicAdd(dr + 9,  c.y);
    atomicAdd(dr + 10, c.z);  atomicAdd(dr + 11, c.w);
    atomicAdd(cnt + dst, 1.0f);
}

__global__ __launch_bounds__(256) void finalize_kernel(
    const float* __restrict__ x, const float* __restrict__ Wl,
    const float* __restrict__ Wr, const float* __restrict__ bias,
    const float* __restrict__ agg, const float* __restrict__ cnt,
    float* __restrict__ out)
{
    __shared__ float sWl[D * D], sWr[D * D], sb[D];
    int t = threadIdx.x;
    if (t < D * D) { sWl[t] = Wl[t]; sWr[t] = Wr[t]; }
    if (t < D) sb[t] = bias[t];
    __syncthreads();
    int i = blockIdx.x * blockDim.x + t;
    if (i >= N_NODES) return;
    float inv = 1.0f / fmaxf(cnt[i], 1.0f);
    float m[D], xi[D];
    const float4* ar = (const float4*)(agg + (size_t)i * D);
    const float4* xr = (const float4*)(x + (size_t)i * D);
    float4 a0 = ar[0], a1 = ar[1], a2 = ar[2];
    float4 x0 = xr[0], x1 = xr[1], x2 = xr[2];
    m[0] = a0.x * inv; m[1] = a0.y * inv; m[2]  = a0.z * inv; m[3]  = a0.w * inv;
    m[4] = a1.x * inv; m[5] = a1.y * inv; m[6]  = a1.z * inv; m[7]  = a1.w * inv;
    m[8] = a2.x * inv; m[9] = a2.y * inv; m[10] = a2.z * inv; m[11] = a2.w * inv;
    xi[0] = x0.x; xi[1] = x0.y; xi[2]  = x0.z; xi[3]  = x0.w;
    xi[4] = x1.x; xi[5] = x1.y; xi[6]  = x1.z; xi[7]  = x1.w;
    xi[8] = x2.x; xi[9] = x2.y; xi[10] = x2.z; xi[11] = x2.w;
    float o[D];
#pragma unroll
    for (int oo = 0; oo < D; ++oo) {
        float acc = sb[oo];
#pragma unroll
        for (int d = 0; d < D; ++d) {
            acc += m[d] * sWl[oo * D + d];
            acc += xi[d] * sWr[oo * D + d];
        }
        o[oo] = acc;
    }
    float4* orow = (float4*)(out + (size_t)i * D);
    orow[0] = make_float4(o[0], o[1], o[2], o[3]);
    orow[1] = make_float4(o[4], o[5], o[6], o[7]);
    orow[2] = make_float4(o[8], o[9], o[10], o[11]);
}

extern "C" void kernel_launch(void* const* d_in, const int* in_sizes, int n_in,
                              void* d_out, int out_size, void* d_ws, size_t ws_size,
                              hipStream_t stream) {
    const float* x    = (const float*)d_in[0];
    const float* Wl   = (const float*)d_in[1];
    const float* Wr   = (const float*)d_in[2];
    const float* bias = (const float*)d_in[3];
    const int*   ei   = (const int*)d_in[4];
    float* out = (float*)d_out;

    size_t sortedBytes = (size_t)N_EDGES * sizeof(unsigned int);     // 25.6 MB
    size_t xbBytes     = (size_t)N_NODES * 8 * sizeof(unsigned int); // 3.2 MB
    size_t binsBytes   = (size_t)NB * sizeof(int);
    size_t baseBytes   = (size_t)(NB + 1) * sizeof(int);
    size_t neededFull = sortedBytes + xbBytes + binsBytes + baseBytes + binsBytes;
    size_t neededMid  = sortedBytes + binsBytes + baseBytes + binsBytes;

    if (ws_size >= neededFull) {
        char* p = (char*)d_ws;
        unsigned int* sorted = (unsigned int*)p;        p += sortedBytes;
        unsigned int* xb     = (unsigned int*)p;        p += xbBytes;
        int* bins   = (int*)p;                          p += binsBytes;
        int* base   = (int*)p;                          p += baseBytes;
        int* cursor = (int*)p;

        hipMemsetAsync(bins, 0, binsBytes, stream);
        prep_kernel<<<(N_NODES + 255) / 256, 256, 0, stream>>>(x, xb);
        hist_kernel<<<NBLK, 256, 0, stream>>>(ei, bins);
        scan_kernel<<<1, 1024, 0, stream>>>(bins, base, cursor);
        scatter_sort_kernel<<<NBLK, 256, 0, stream>>>(ei, cursor, sorted);
        agg_finalize_kernel<<<NB, 256, 0, stream>>>(sorted, base, xb, x, Wl, Wr, bias, out);
    } else if (ws_size >= neededMid) {
        char* p = (char*)d_ws;
        unsigned int* sorted = (unsigned int*)p;        p += sortedBytes;
        int* bins   = (int*)p;                          p += binsBytes;
        int* base   = (int*)p;                          p += baseBytes;
        int* cursor = (int*)p;

        hipMemsetAsync(bins, 0, binsBytes, stream);
        hist_kernel<<<NBLK, 256, 0, stream>>>(ei, bins);
        scan_kernel<<<1, 1024, 0, stream>>>(bins, base, cursor);
        scatter_sort_kernel<<<NBLK, 256, 0, stream>>>(ei, cursor, sorted);
        agg_finalize_f32_kernel<<<NB, 256, 0, stream>>>(sorted, base, x, Wl, Wr, bias, out);
    } else {
        float* agg = (float*)d_ws;
        float* cnt = agg + (size_t)N_NODES * D;
        hipMemsetAsync(d_ws, 0, ((size_t)N_NODES * D + N_NODES) * sizeof(float), stream);
        scatter_kernel<<<(N_EDGES + 255) / 256, 256, 0, stream>>>(ei, x, agg, cnt);
        finalize_kernel<<<(N_NODES + 255) / 256, 256, 0, stream>>>(x, Wl, Wr, bias, agg, cnt, out);
    }
}